// Round 10
// baseline (2240.675 us; speedup 1.0000x reference)
//
#include <hip/hip_runtime.h>
#include <math.h>

// GCN 2-layer: out = relu( relu( (A @ x) @ W1 + b1 ) @ W2 + b2 )
// A = D^-1/2 (Adj + I) D^-1/2 (weighted, self-loop weight 1).
// Aggregation at d_in=128 ((A@x)@W1 == A@(x@W1), linearity).
// R10: R9 with the hipDeviceAttributeMultiprocessorCount typo fixed.
// Fused prologue k_pre (init/cvt->hist->scanA->scanB->scanC->scatter->
// gather) with hand grid barriers on an occupancy-sized grid; k_mlp
// unchanged. Fallback: proven R7 multi-kernel path.

typedef __attribute__((ext_vector_type(8))) short short8v;   // 8 bf16 = 4 VGPR
typedef __attribute__((ext_vector_type(4))) float floatx4;   // MFMA C/D

__device__ __forceinline__ short f2bf(float f) {             // RNE f32->bf16
    unsigned u = __builtin_bit_cast(unsigned, f);
    unsigned r = (u + 0x7FFFu + ((u >> 16) & 1u)) >> 16;
    return (short)r;
}
__device__ __forceinline__ float bfu_lo(unsigned u) {
    return __builtin_bit_cast(float, u << 16);
}
__device__ __forceinline__ float bfu_hi(unsigned u) {
    return __builtin_bit_cast(float, u & 0xFFFF0000u);
}

// Grid barrier: one dedicated counter per barrier instance (zeroed by
// hipMemsetAsync before launch). Release-add arrive, acquire-load spin,
// __threadfence on both sides (agent-scope -> visibility across XCDs).
__device__ __forceinline__ void gridbar(int* cnt, int nblk) {
    __syncthreads();
    __threadfence();
    if (threadIdx.x == 0) {
        __hip_atomic_fetch_add(cnt, 1, __ATOMIC_ACQ_REL, __HIP_MEMORY_SCOPE_AGENT);
        while (__hip_atomic_load(cnt, __ATOMIC_ACQUIRE, __HIP_MEMORY_SCOPE_AGENT) < nblk)
            __builtin_amdgcn_s_sleep(2);
    }
    __syncthreads();
    __threadfence();
}

// ---------------- fused prologue: phases 0-6 ----------------
__global__ __launch_bounds__(256, 8) void k_pre(
    const float* __restrict__ x, const int* __restrict__ ei,
    const float* __restrict__ ew,
    const float* __restrict__ W1, const float* __restrict__ W2,
    int* __restrict__ bars,
    float* __restrict__ deg, int* __restrict__ counts,
    int* __restrict__ offsets, int* __restrict__ blockSum,
    int2* __restrict__ sedge, short* __restrict__ W1t, short* __restrict__ W2t,
    short* __restrict__ xbf, short* __restrict__ ybf,
    int n, int E, int NB, int NROWS) {
    __shared__ int sdata[256];
    const int tid = threadIdx.x;
    const int bid = blockIdx.x;
    const int nblk = gridDim.x;
    const int gsz = nblk * 256;
    const int gi0 = bid * 256 + tid;
    const int* src = ei;
    const int* dst = ei + E;

    // ---- phase 0: counts=0, deg=1, W transpose+cvt, x->bf16 ----
    {
        const int nx4 = n * 32;
        for (int i = gi0; i < nx4; i += gsz) {
            float4 v = ((const float4*)x)[i];
            short4 s;
            s.x = f2bf(v.x); s.y = f2bf(v.y); s.z = f2bf(v.z); s.w = f2bf(v.w);
            *(short4*)&xbf[(size_t)i * 4] = s;
        }
        for (int i = gi0; i < n; i += gsz) { counts[i] = 0; deg[i] = 1.0f; }
        for (int i = gi0; i < 65536; i += gsz) {
            int c = i >> 7, k = i & 127;
            W1t[i] = f2bf(W1[k * 512 + c]);
        }
        for (int i = gi0; i < 65536; i += gsz) {
            int c = i >> 9, k = i & 511;
            W2t[i] = f2bf(W2[k * 128 + c]);
        }
    }
    gridbar(&bars[0], nblk);

    // ---- phase 1: histogram + weighted degree ----
    for (int e = gi0; e < E; e += gsz) {
        int d = dst[e];
        atomicAdd(&counts[d], 1);
        atomicAdd(&deg[d], ew[e]);
    }
    gridbar(&bars[1], nblk);

    // ---- phase 2: scanA (per-256-chunk exclusive scan) + deg->dinv ----
    for (int cb = bid; cb < NB; cb += nblk) {
        const int i = cb * 256 + tid;
        int c = (i < n) ? counts[i] : 0;
        __syncthreads();
        sdata[tid] = c;
        __syncthreads();
#pragma unroll
        for (int off = 1; off < 256; off <<= 1) {
            int t = (tid >= off) ? sdata[tid - off] : 0;
            __syncthreads();
            sdata[tid] += t;
            __syncthreads();
        }
        if (i < n) offsets[i] = sdata[tid] - c;
        if (tid == 255) blockSum[cb] = sdata[255];
        if (i < n) {
            float d = deg[i];
            deg[i] = (d > 0.f) ? rsqrtf(d) : 0.f;
        }
    }
    gridbar(&bars[2], nblk);

    // ---- phase 3: scanB (block 0 scans NB block sums, NB<=256) ----
    if (bid == 0) {
        int v = (tid < NB) ? blockSum[tid] : 0;
        sdata[tid] = v;
        __syncthreads();
#pragma unroll
        for (int off = 1; off < 256; off <<= 1) {
            int t = (tid >= off) ? sdata[tid - off] : 0;
            __syncthreads();
            sdata[tid] += t;
            __syncthreads();
        }
        if (tid < NB) blockSum[tid] = sdata[tid] - v;
    }
    gridbar(&bars[3], nblk);

    // ---- phase 4: scanC (add block prefix) ----
    for (int i = gi0; i < n; i += gsz) offsets[i] += blockSum[i >> 8];
    gridbar(&bars[4], nblk);

    // ---- phase 5: scatter into dst-sorted slots (offsets -> end ptrs) ----
    for (int e = gi0; e < E; e += gsz) {
        int s = src[e];
        int d = dst[e];
        float coef = deg[s] * ew[e] * deg[d];   // deg holds dinv now
        int pos = atomicAdd(&offsets[d], 1);
        sedge[pos] = make_int2(s, __builtin_bit_cast(int, coef));
    }
    gridbar(&bars[5], nblk);

    // ---- phase 6: pull gather (one wave per node), bf16 y out ----
    {
        const unsigned* xbf_u = (const unsigned*)xbf;
        unsigned* ybf_u = (unsigned*)ybf;
        const int lane = tid & 63;
        const int w0 = gi0 >> 6;
        const int wstride = gsz >> 6;
        for (int wid = w0; wid < NROWS; wid += wstride) {
            if (wid >= n) {                     // zero pad rows
                ybf_u[(size_t)wid * 64 + lane] = 0u;
                continue;
            }
            int o1 = offsets[wid];              // post-scatter: end of range
            int o0 = o1 - counts[wid];
            float di = deg[wid];                // dinv
            unsigned xs = xbf_u[(size_t)wid * 64 + lane];
            float2 acc;
            acc.x = di * di * bfu_lo(xs);
            acc.y = di * di * bfu_hi(xs);
            int j = o0;
            for (; j + 4 <= o1; j += 4) {
                int2 e0 = sedge[j], e1 = sedge[j + 1], e2 = sedge[j + 2], e3 = sedge[j + 3];
                unsigned v0 = xbf_u[(size_t)e0.x * 64 + lane];
                unsigned v1 = xbf_u[(size_t)e1.x * 64 + lane];
                unsigned v2 = xbf_u[(size_t)e2.x * 64 + lane];
                unsigned v3 = xbf_u[(size_t)e3.x * 64 + lane];
                float c0 = __builtin_bit_cast(float, e0.y);
                float c1 = __builtin_bit_cast(float, e1.y);
                float c2 = __builtin_bit_cast(float, e2.y);
                float c3 = __builtin_bit_cast(float, e3.y);
                acc.x = fmaf(c0, bfu_lo(v0), acc.x); acc.y = fmaf(c0, bfu_hi(v0), acc.y);
                acc.x = fmaf(c1, bfu_lo(v1), acc.x); acc.y = fmaf(c1, bfu_hi(v1), acc.y);
                acc.x = fmaf(c2, bfu_lo(v2), acc.x); acc.y = fmaf(c2, bfu_hi(v2), acc.y);
                acc.x = fmaf(c3, bfu_lo(v3), acc.x); acc.y = fmaf(c3, bfu_hi(v3), acc.y);
            }
            for (; j < o1; ++j) {
                int2 e = sedge[j];
                unsigned v = xbf_u[(size_t)e.x * 64 + lane];
                float c = __builtin_bit_cast(float, e.y);
                acc.x = fmaf(c, bfu_lo(v), acc.x);
                acc.y = fmaf(c, bfu_hi(v), acc.y);
            }
            unsigned lo = (unsigned)(unsigned short)f2bf(acc.x);
            unsigned hi = (unsigned)(unsigned short)f2bf(acc.y);
            ybf_u[(size_t)wid * 64 + lane] = lo | (hi << 16);
        }
    }
    // kernel end = implicit device-wide visibility before k_mlp
}

// ---------------- MFMA MLP (unchanged from R7, proven) ----------------
__global__ __launch_bounds__(256) void k_mlp(const short* __restrict__ ybf,
                                             const short* __restrict__ W1t,
                                             const float* __restrict__ b1,
                                             const short* __restrict__ W2t,
                                             const float* __restrict__ b2,
                                             float* __restrict__ out, int n) {
    __shared__ __align__(16) short hlds[32 * 512];
    const int tid  = threadIdx.x;
    const int wave = tid >> 6;
    const int lane = tid & 63;
    const int l15  = lane & 15;
    const int lg   = lane >> 4;
    const int row0 = blockIdx.x * 32;

    const int cb1 = wave * 128;
    floatx4 acc[2][8];
#pragma unroll
    for (int m = 0; m < 2; ++m)
#pragma unroll
        for (int nn = 0; nn < 8; ++nn) acc[m][nn] = (floatx4)0.0f;

#pragma unroll
    for (int kk = 0; kk < 4; ++kk) {
        const int k0 = kk * 32 + lg * 8;
        short8v bf[8];
#pragma unroll
        for (int nn = 0; nn < 8; ++nn)
            bf[nn] = *(const short8v*)(W1t + (size_t)(cb1 + nn * 16 + l15) * 128 + k0);
#pragma unroll
        for (int m = 0; m < 2; ++m) {
            short8v a = *(const short8v*)(ybf + (size_t)(row0 + m * 16 + l15) * 128 + k0);
#pragma unroll
            for (int nn = 0; nn < 8; ++nn)
                acc[m][nn] = __builtin_amdgcn_mfma_f32_16x16x32_bf16(a, bf[nn], acc[m][nn], 0, 0, 0);
        }
    }

#pragma unroll
    for (int m = 0; m < 2; ++m)
#pragma unroll
        for (int nn = 0; nn < 8; ++nn) {
            const int c = cb1 + nn * 16 + l15;
            const float bb = b1[c];
#pragma unroll
            for (int i = 0; i < 4; ++i) {
                const int r = m * 16 + lg * 4 + i;
                float v = acc[m][nn][i] + bb;
                v = v > 0.f ? v : 0.f;
                hlds[r * 512 + (c ^ ((r & 7) << 3))] = f2bf(v);
            }
        }
    __syncthreads();

    const int cb2 = wave * 32;
    floatx4 acc2[2][2];
#pragma unroll
    for (int m = 0; m < 2; ++m)
#pragma unroll
        for (int nn = 0; nn < 2; ++nn) acc2[m][nn] = (floatx4)0.0f;

#pragma unroll
    for (int kk = 0; kk < 16; ++kk) {
        const int k0 = kk * 32 + lg * 8;
        short8v bf2[2];
#pragma unroll
        for (int nn = 0; nn < 2; ++nn)
            bf2[nn] = *(const short8v*)(W2t + (size_t)(cb2 + nn * 16 + l15) * 512 + k0);
#pragma unroll
        for (int m = 0; m < 2; ++m) {
            const int r = m * 16 + l15;
            short8v a = *(const short8v*)&hlds[r * 512 + (k0 ^ ((r & 7) << 3))];
#pragma unroll
            for (int nn = 0; nn < 2; ++nn)
                acc2[m][nn] = __builtin_amdgcn_mfma_f32_16x16x32_bf16(a, bf2[nn], acc2[m][nn], 0, 0, 0);
        }
    }

#pragma unroll
    for (int m = 0; m < 2; ++m)
#pragma unroll
        for (int nn = 0; nn < 2; ++nn) {
            const int c = cb2 + nn * 16 + l15;
            const float bb = b2[c];
#pragma unroll
            for (int i = 0; i < 4; ++i) {
                const int rg = row0 + m * 16 + lg * 4 + i;
                if (rg < n) {
                    float v = acc2[m][nn][i] + bb;
                    out[(size_t)rg * 128 + c] = v > 0.f ? v : 0.f;
                }
            }
        }
}

// ---------------- fallback kernels (R7, proven) ----------------
__global__ __launch_bounds__(256) void k_initprep(int* __restrict__ counts,
                                                  float* __restrict__ deg, int n,
                                                  const float* __restrict__ W1,
                                                  const float* __restrict__ W2,
                                                  short* __restrict__ W1t,
                                                  short* __restrict__ W2t,
                                                  const float* __restrict__ x,
                                                  short* __restrict__ xbf) {
    int i = blockIdx.x * 256 + threadIdx.x;
    int nx4 = n * 32;
    if (i < nx4) {
        float4 v = ((const float4*)x)[i];
        short4 s;
        s.x = f2bf(v.x); s.y = f2bf(v.y); s.z = f2bf(v.z); s.w = f2bf(v.w);
        *(short4*)&xbf[(size_t)i * 4] = s;
    }
    if (i < n) { counts[i] = 0; deg[i] = 1.0f; }
    if (i < 65536) {
        int c = i >> 7, k = i & 127;
        W1t[i] = f2bf(W1[k * 512 + c]);
    } else if (i < 131072) {
        int j = i - 65536;
        int c = j >> 9, k = j & 511;
        W2t[j] = f2bf(W2[k * 128 + c]);
    }
}

__global__ __launch_bounds__(256) void k_hist(const int* __restrict__ dst,
                                              const float* __restrict__ ew,
                                              int* __restrict__ counts,
                                              float* __restrict__ deg, int E) {
    int e = blockIdx.x * 256 + threadIdx.x;
    if (e < E) {
        int d = dst[e];
        atomicAdd(&counts[d], 1);
        atomicAdd(&deg[d], ew[e]);
    }
}

__global__ __launch_bounds__(256) void k_scanA(const int* __restrict__ counts,
                                               int* __restrict__ offsets,
                                               int* __restrict__ blockSum,
                                               float* __restrict__ deg, int n) {
    __shared__ int sdata[256];
    const int tid = threadIdx.x;
    const int i = blockIdx.x * 256 + tid;
    int c = (i < n) ? counts[i] : 0;
    sdata[tid] = c;
    __syncthreads();
#pragma unroll
    for (int off = 1; off < 256; off <<= 1) {
        int t = (tid >= off) ? sdata[tid - off] : 0;
        __syncthreads();
        sdata[tid] += t;
        __syncthreads();
    }
    if (i < n) offsets[i] = sdata[tid] - c;
    if (tid == 255) blockSum[blockIdx.x] = sdata[255];
    if (i < n) {
        float d = deg[i];
        deg[i] = (d > 0.f) ? rsqrtf(d) : 0.f;
    }
}

__global__ __launch_bounds__(256) void k_scanB(int* __restrict__ blockSum, int nb) {
    __shared__ int sdata[256];
    const int tid = threadIdx.x;
    int v = (tid < nb) ? blockSum[tid] : 0;
    sdata[tid] = v;
    __syncthreads();
#pragma unroll
    for (int off = 1; off < 256; off <<= 1) {
        int t = (tid >= off) ? sdata[tid - off] : 0;
        __syncthreads();
        sdata[tid] += t;
        __syncthreads();
    }
    if (tid < nb) blockSum[tid] = sdata[tid] - v;
}

__global__ __launch_bounds__(256) void k_scanC(int* __restrict__ offsets,
                                               const int* __restrict__ blockSum, int n) {
    const int i = blockIdx.x * 256 + threadIdx.x;
    if (i < n) offsets[i] += blockSum[i >> 8];
}

__global__ __launch_bounds__(256) void k_scatter(const int* __restrict__ src,
                                                 const int* __restrict__ dst,
                                                 const float* __restrict__ ew,
                                                 const float* __restrict__ dinv,
                                                 int* __restrict__ offsets,
                                                 int2* __restrict__ sedge, int E) {
    int e = blockIdx.x * 256 + threadIdx.x;
    if (e >= E) return;
    int s = src[e];
    int d = dst[e];
    float coef = dinv[s] * ew[e] * dinv[d];
    int pos = atomicAdd(&offsets[d], 1);
    sedge[pos] = make_int2(s, __builtin_bit_cast(int, coef));
}

__global__ __launch_bounds__(256) void k_gather(const int* __restrict__ offsets,
                                                const int* __restrict__ counts,
                                                const int2* __restrict__ sedge,
                                                const float* __restrict__ dinv,
                                                const unsigned* __restrict__ xbf_u,
                                                unsigned* __restrict__ ybf_u, int n,
                                                int NROWS) {
    int wid = (blockIdx.x * 256 + threadIdx.x) >> 6;
    if (wid >= NROWS) return;
    int lane = threadIdx.x & 63;
    if (wid >= n) { ybf_u[(size_t)wid * 64 + lane] = 0u; return; }
    int o1 = offsets[wid];
    int o0 = o1 - counts[wid];
    float di = dinv[wid];
    unsigned xs = xbf_u[(size_t)wid * 64 + lane];
    float2 acc;
    acc.x = di * di * bfu_lo(xs);
    acc.y = di * di * bfu_hi(xs);
    int j = o0;
    for (; j + 4 <= o1; j += 4) {
        int2 e0 = sedge[j], e1 = sedge[j + 1], e2 = sedge[j + 2], e3 = sedge[j + 3];
        unsigned v0 = xbf_u[(size_t)e0.x * 64 + lane];
        unsigned v1 = xbf_u[(size_t)e1.x * 64 + lane];
        unsigned v2 = xbf_u[(size_t)e2.x * 64 + lane];
        unsigned v3 = xbf_u[(size_t)e3.x * 64 + lane];
        float c0 = __builtin_bit_cast(float, e0.y);
        float c1 = __builtin_bit_cast(float, e1.y);
        float c2 = __builtin_bit_cast(float, e2.y);
        float c3 = __builtin_bit_cast(float, e3.y);
        acc.x = fmaf(c0, bfu_lo(v0), acc.x); acc.y = fmaf(c0, bfu_hi(v0), acc.y);
        acc.x = fmaf(c1, bfu_lo(v1), acc.x); acc.y = fmaf(c1, bfu_hi(v1), acc.y);
        acc.x = fmaf(c2, bfu_lo(v2), acc.x); acc.y = fmaf(c2, bfu_hi(v2), acc.y);
        acc.x = fmaf(c3, bfu_lo(v3), acc.x); acc.y = fmaf(c3, bfu_hi(v3), acc.y);
    }
    for (; j < o1; ++j) {
        int2 e = sedge[j];
        unsigned v = xbf_u[(size_t)e.x * 64 + lane];
        float c = __builtin_bit_cast(float, e.y);
        acc.x = fmaf(c, bfu_lo(v), acc.x);
        acc.y = fmaf(c, bfu_hi(v), acc.y);
    }
    unsigned lo = (unsigned)(unsigned short)f2bf(acc.x);
    unsigned hi = (unsigned)(unsigned short)f2bf(acc.y);
    ybf_u[(size_t)wid * 64 + lane] = lo | (hi << 16);
}

extern "C" void kernel_launch(void* const* d_in, const int* in_sizes, int n_in,
                              void* d_out, int out_size, void* d_ws, size_t ws_size,
                              hipStream_t stream) {
    const float* x  = (const float*)d_in[0];
    const int*   ei = (const int*)d_in[1];
    const float* ew = (const float*)d_in[2];
    const float* W1 = (const float*)d_in[3];
    const float* b1 = (const float*)d_in[4];
    const float* W2 = (const float*)d_in[5];
    const float* b2 = (const float*)d_in[6];
    float* out = (float*)d_out;

    int N = in_sizes[0] / 128;
    int E = in_sizes[2];
    int NB  = (N + 255) / 256;     // 196 (<=256 required by scanB)
    int NBM = (N + 31) / 32;       // mlp tiles
    int NROWS = NBM * 32;

    // ws layout (bars first, 64B)
    int*   bars     = (int*)d_ws;              // 16 ints
    float* deg      = (float*)(bars + 16);     // N (becomes dinv)
    int*   counts   = (int*)(deg + N);         // N
    int*   offsets  = counts + N;              // N (end-pointers post-scatter)
    int*   blockSum = offsets + N;             // 1024
    int2*  sedge    = (int2*)((((uintptr_t)(blockSum + 1024)) + 15) & ~(uintptr_t)15); // E
    short* W1t      = (short*)(sedge + E);     // 65536 bf16
    short* W2t      = W1t + 65536;             // 65536 bf16
    short* xbf      = (short*)((((uintptr_t)(W2t + 65536)) + 15) & ~(uintptr_t)15);    // N*128
    short* ybf      = xbf + (size_t)N * 128;   // NROWS*128

    // Size k_pre's grid so all blocks are co-resident (hand barrier safe).
    int occ = 0, nCU = 0, dev = 0;
    (void)hipGetDevice(&dev);
    hipError_t e1 = hipOccupancyMaxActiveBlocksPerMultiprocessor(
        &occ, (const void*)k_pre, 256, 0);
    hipError_t e2 = hipDeviceGetAttribute(&nCU, hipDeviceAttributeMultiprocessorCount, dev);
    long gridBlocks = (e1 == hipSuccess && e2 == hipSuccess) ? (long)occ * nCU : 0;
    if (gridBlocks > 4096) gridBlocks = 4096;

    if (gridBlocks >= 256) {
        (void)hipMemsetAsync(bars, 0, 16 * sizeof(int), stream);
        k_pre<<<(int)gridBlocks, 256, 0, stream>>>(
            x, ei, ew, W1, W2, bars, deg, counts, offsets, blockSum,
            sedge, W1t, W2t, xbf, ybf, N, E, NB, NROWS);
    } else {
        // fallback: proven R7 multi-kernel path
        int nb;
        nb = (N * 32 + 255) / 256;
        k_initprep<<<nb, 256, 0, stream>>>(counts, deg, N, W1, W2, W1t, W2t, x, xbf);
        nb = (E + 255) / 256;
        k_hist<<<nb, 256, 0, stream>>>(ei + E, ew, counts, deg, E);
        k_scanA<<<NB, 256, 0, stream>>>(counts, offsets, blockSum, deg, N);
        k_scanB<<<1, 256, 0, stream>>>(blockSum, NB);
        k_scanC<<<NB, 256, 0, stream>>>(offsets, blockSum, N);
        nb = (E + 255) / 256;
        k_scatter<<<nb, 256, 0, stream>>>(ei, ei + E, ew, deg, offsets, sedge, E);
        nb = (NROWS * 64 + 255) / 256;
        k_gather<<<nb, 256, 0, stream>>>(offsets, counts, sedge, deg,
                                         (const unsigned*)xbf, (unsigned*)ybf, N, NROWS);
    }
    k_mlp<<<NBM, 256, 0, stream>>>(ybf, W1t, b1, W2t, b2, out, N);
}

// Round 11
// 275.990 us; speedup vs baseline: 8.1187x; 8.1187x over previous
//
#include <hip/hip_runtime.h>
#include <math.h>

// GCN 2-layer: out = relu( relu( (A @ x) @ W1 + b1 ) @ W2 + b2 )
// A = D^-1/2 (Adj + I) D^-1/2 (weighted, self-loop weight 1).
// Aggregation at d_in=128 ((A@x)@W1 == A@(x@W1), linearity).
// R11: revert to proven R7 multi-kernel path (R10 mega-kernel: grid
// barrier cost ~380us/barrier at 2048 blocks -- dead end; launch gaps
// proven small). One change vs R7: k_mlp stages the y-tile once into
// swizzled LDS (kills 4x-redundant latency-exposed global A loads).

typedef __attribute__((ext_vector_type(8))) short short8v;   // 8 bf16 = 4 VGPR
typedef __attribute__((ext_vector_type(4))) float floatx4;   // MFMA C/D

__device__ __forceinline__ short f2bf(float f) {             // RNE f32->bf16
    unsigned u = __builtin_bit_cast(unsigned, f);
    unsigned r = (u + 0x7FFFu + ((u >> 16) & 1u)) >> 16;
    return (short)r;
}
__device__ __forceinline__ float bfu_lo(unsigned u) {
    return __builtin_bit_cast(float, u << 16);
}
__device__ __forceinline__ float bfu_hi(unsigned u) {
    return __builtin_bit_cast(float, u & 0xFFFF0000u);
}

// ---------------- init + weight prep + x->bf16 (merged) ----------------
__global__ __launch_bounds__(256) void k_initprep(int* __restrict__ counts,
                                                  float* __restrict__ deg, int n,
                                                  const float* __restrict__ W1,
                                                  const float* __restrict__ W2,
                                                  short* __restrict__ W1t,
                                                  short* __restrict__ W2t,
                                                  const float* __restrict__ x,
                                                  short* __restrict__ xbf) {
    int i = blockIdx.x * 256 + threadIdx.x;
    int nx4 = n * 32;
    if (i < nx4) {
        float4 v = ((const float4*)x)[i];
        short4 s;
        s.x = f2bf(v.x); s.y = f2bf(v.y); s.z = f2bf(v.z); s.w = f2bf(v.w);
        *(short4*)&xbf[(size_t)i * 4] = s;
    }
    if (i < n) { counts[i] = 0; deg[i] = 1.0f; }
    if (i < 65536) {
        int c = i >> 7, k = i & 127;
        W1t[i] = f2bf(W1[k * 512 + c]);
    } else if (i < 131072) {
        int j = i - 65536;
        int c = j >> 9, k = j & 511;
        W2t[j] = f2bf(W2[k * 128 + c]);
    }
}

__global__ __launch_bounds__(256) void k_hist(const int* __restrict__ dst,
                                              const float* __restrict__ ew,
                                              int* __restrict__ counts,
                                              float* __restrict__ deg, int E) {
    int e = blockIdx.x * 256 + threadIdx.x;
    if (e < E) {
        int d = dst[e];
        atomicAdd(&counts[d], 1);
        atomicAdd(&deg[d], ew[e]);
    }
}

__global__ __launch_bounds__(256) void k_scanA(const int* __restrict__ counts,
                                               int* __restrict__ offsets,
                                               int* __restrict__ blockSum,
                                               float* __restrict__ deg, int n) {
    __shared__ int sdata[256];
    const int tid = threadIdx.x;
    const int i = blockIdx.x * 256 + tid;
    int c = (i < n) ? counts[i] : 0;
    sdata[tid] = c;
    __syncthreads();
#pragma unroll
    for (int off = 1; off < 256; off <<= 1) {
        int t = (tid >= off) ? sdata[tid - off] : 0;
        __syncthreads();
        sdata[tid] += t;
        __syncthreads();
    }
    if (i < n) offsets[i] = sdata[tid] - c;
    if (tid == 255) blockSum[blockIdx.x] = sdata[255];
    if (i < n) {
        float d = deg[i];
        deg[i] = (d > 0.f) ? rsqrtf(d) : 0.f;
    }
}

__global__ __launch_bounds__(256) void k_scanB(int* __restrict__ blockSum, int nb) {
    __shared__ int sdata[256];
    const int tid = threadIdx.x;
    int v = (tid < nb) ? blockSum[tid] : 0;
    sdata[tid] = v;
    __syncthreads();
#pragma unroll
    for (int off = 1; off < 256; off <<= 1) {
        int t = (tid >= off) ? sdata[tid - off] : 0;
        __syncthreads();
        sdata[tid] += t;
        __syncthreads();
    }
    if (tid < nb) blockSum[tid] = sdata[tid] - v;
}

__global__ __launch_bounds__(256) void k_scanC(int* __restrict__ offsets,
                                               const int* __restrict__ blockSum, int n) {
    const int i = blockIdx.x * 256 + threadIdx.x;
    if (i < n) offsets[i] += blockSum[i >> 8];
}

// scatter edges into dst-sorted slots; bumps offsets[d] (post: end of range).
__global__ __launch_bounds__(256) void k_scatter(const int* __restrict__ src,
                                                 const int* __restrict__ dst,
                                                 const float* __restrict__ ew,
                                                 const float* __restrict__ dinv,
                                                 int* __restrict__ offsets,
                                                 int2* __restrict__ sedge, int E) {
    int e = blockIdx.x * 256 + threadIdx.x;
    if (e >= E) return;
    int s = src[e];
    int d = dst[e];
    float coef = dinv[s] * ew[e] * dinv[d];
    int pos = atomicAdd(&offsets[d], 1);
    sedge[pos] = make_int2(s, __builtin_bit_cast(int, coef));
}

// pull gather (bf16 x): one wave per node, f32 accumulate, bf16 y out.
__global__ __launch_bounds__(256) void k_gather(const int* __restrict__ offsets,
                                                const int* __restrict__ counts,
                                                const int2* __restrict__ sedge,
                                                const float* __restrict__ dinv,
                                                const unsigned* __restrict__ xbf_u,
                                                unsigned* __restrict__ ybf_u, int n) {
    int wid = (blockIdx.x * 256 + threadIdx.x) >> 6;
    if (wid >= n) return;
    int lane = threadIdx.x & 63;
    int o1 = offsets[wid];               // post-scatter: end of range
    int o0 = o1 - counts[wid];
    float di = dinv[wid];
    unsigned xs = xbf_u[(size_t)wid * 64 + lane];
    float2 acc;
    acc.x = di * di * bfu_lo(xs);
    acc.y = di * di * bfu_hi(xs);
    int j = o0;
    for (; j + 4 <= o1; j += 4) {
        int2 e0 = sedge[j], e1 = sedge[j + 1], e2 = sedge[j + 2], e3 = sedge[j + 3];
        unsigned v0 = xbf_u[(size_t)e0.x * 64 + lane];
        unsigned v1 = xbf_u[(size_t)e1.x * 64 + lane];
        unsigned v2 = xbf_u[(size_t)e2.x * 64 + lane];
        unsigned v3 = xbf_u[(size_t)e3.x * 64 + lane];
        float c0 = __builtin_bit_cast(float, e0.y);
        float c1 = __builtin_bit_cast(float, e1.y);
        float c2 = __builtin_bit_cast(float, e2.y);
        float c3 = __builtin_bit_cast(float, e3.y);
        acc.x = fmaf(c0, bfu_lo(v0), acc.x); acc.y = fmaf(c0, bfu_hi(v0), acc.y);
        acc.x = fmaf(c1, bfu_lo(v1), acc.x); acc.y = fmaf(c1, bfu_hi(v1), acc.y);
        acc.x = fmaf(c2, bfu_lo(v2), acc.x); acc.y = fmaf(c2, bfu_hi(v2), acc.y);
        acc.x = fmaf(c3, bfu_lo(v3), acc.x); acc.y = fmaf(c3, bfu_hi(v3), acc.y);
    }
    for (; j < o1; ++j) {
        int2 e = sedge[j];
        unsigned v = xbf_u[(size_t)e.x * 64 + lane];
        float c = __builtin_bit_cast(float, e.y);
        acc.x = fmaf(c, bfu_lo(v), acc.x);
        acc.y = fmaf(c, bfu_hi(v), acc.y);
    }
    unsigned lo = (unsigned)(unsigned short)f2bf(acc.x);
    unsigned hi = (unsigned)(unsigned short)f2bf(acc.y);
    ybf_u[(size_t)wid * 64 + lane] = lo | (hi << 16);
}

// ---------------- MFMA MLP: LDS-staged A tile ----------------
// 32 rows/block, 4 waves. y tile (8KB) staged ONCE into swizzled LDS
// (R7 loaded it 4x redundantly from global per wave). GEMM1: wave w ->
// h cols [w*128,+128). GEMM2: wave w -> out cols [w*32,+32).
__global__ __launch_bounds__(256) void k_mlp(const short* __restrict__ ybf,
                                             const short* __restrict__ W1t,
                                             const float* __restrict__ b1,
                                             const short* __restrict__ W2t,
                                             const float* __restrict__ b2,
                                             float* __restrict__ out, int n) {
    __shared__ __align__(16) short ylds[32 * 128];   // 8KB
    __shared__ __align__(16) short hlds[32 * 512];   // 32KB
    const int tid  = threadIdx.x;
    const int wave = tid >> 6;
    const int lane = tid & 63;
    const int l15  = lane & 15;
    const int lg   = lane >> 4;
    const int row0 = blockIdx.x * 32;

    // stage y tile: 512 x 16B chunks, coalesced, XOR-swizzled store
#pragma unroll
    for (int i = 0; i < 2; ++i) {
        const int idx = tid + i * 256;       // 0..511
        const int r   = idx >> 4;            // row 0..31
        const int c16 = idx & 15;            // 16B chunk in row
        short8v v = *(const short8v*)(ybf + (size_t)(row0 + r) * 128 + c16 * 8);
        *(short8v*)&ylds[r * 128 + ((c16 * 8) ^ ((r & 7) << 3))] = v;
    }
    __syncthreads();

    // ---- GEMM1: h[32][512] = relu(y @ W1 + b1); wave cols cb1..+127
    const int cb1 = wave * 128;
    floatx4 acc[2][8];
#pragma unroll
    for (int m = 0; m < 2; ++m)
#pragma unroll
        for (int nn = 0; nn < 8; ++nn) acc[m][nn] = (floatx4)0.0f;

#pragma unroll
    for (int kk = 0; kk < 4; ++kk) {
        const int k0 = kk * 32 + lg * 8;
        short8v bf[8];
#pragma unroll
        for (int nn = 0; nn < 8; ++nn)
            bf[nn] = *(const short8v*)(W1t + (size_t)(cb1 + nn * 16 + l15) * 128 + k0);
#pragma unroll
        for (int m = 0; m < 2; ++m) {
            const int r = m * 16 + l15;
            short8v a = *(const short8v*)&ylds[r * 128 + (k0 ^ ((r & 7) << 3))];
#pragma unroll
            for (int nn = 0; nn < 8; ++nn)
                acc[m][nn] = __builtin_amdgcn_mfma_f32_16x16x32_bf16(a, bf[nn], acc[m][nn], 0, 0, 0);
        }
    }

    // epilogue: bias + relu + bf16, swizzled LDS write
#pragma unroll
    for (int m = 0; m < 2; ++m)
#pragma unroll
        for (int nn = 0; nn < 8; ++nn) {
            const int c = cb1 + nn * 16 + l15;
            const float bb = b1[c];
#pragma unroll
            for (int i = 0; i < 4; ++i) {
                const int r = m * 16 + lg * 4 + i;
                float v = acc[m][nn][i] + bb;
                v = v > 0.f ? v : 0.f;
                hlds[r * 512 + (c ^ ((r & 7) << 3))] = f2bf(v);
            }
        }
    __syncthreads();

    // ---- GEMM2: out[32][128] = relu(h @ W2 + b2); wave cols cb2..+31
    const int cb2 = wave * 32;
    floatx4 acc2[2][2];
#pragma unroll
    for (int m = 0; m < 2; ++m)
#pragma unroll
        for (int nn = 0; nn < 2; ++nn) acc2[m][nn] = (floatx4)0.0f;

#pragma unroll
    for (int kk = 0; kk < 16; ++kk) {
        const int k0 = kk * 32 + lg * 8;
        short8v bf2[2];
#pragma unroll
        for (int nn = 0; nn < 2; ++nn)
            bf2[nn] = *(const short8v*)(W2t + (size_t)(cb2 + nn * 16 + l15) * 512 + k0);
#pragma unroll
        for (int m = 0; m < 2; ++m) {
            const int r = m * 16 + l15;
            short8v a = *(const short8v*)&hlds[r * 512 + (k0 ^ ((r & 7) << 3))];
#pragma unroll
            for (int nn = 0; nn < 2; ++nn)
                acc2[m][nn] = __builtin_amdgcn_mfma_f32_16x16x32_bf16(a, bf2[nn], acc2[m][nn], 0, 0, 0);
        }
    }

#pragma unroll
    for (int m = 0; m < 2; ++m)
#pragma unroll
        for (int nn = 0; nn < 2; ++nn) {
            const int c = cb2 + nn * 16 + l15;
            const float bb = b2[c];
#pragma unroll
            for (int i = 0; i < 4; ++i) {
                const int rg = row0 + m * 16 + lg * 4 + i;
                if (rg < n) {
                    float v = acc2[m][nn][i] + bb;
                    out[(size_t)rg * 128 + c] = v > 0.f ? v : 0.f;
                }
            }
        }
}

extern "C" void kernel_launch(void* const* d_in, const int* in_sizes, int n_in,
                              void* d_out, int out_size, void* d_ws, size_t ws_size,
                              hipStream_t stream) {
    const float* x  = (const float*)d_in[0];
    const int*   ei = (const int*)d_in[1];
    const float* ew = (const float*)d_in[2];
    const float* W1 = (const float*)d_in[3];
    const float* b1 = (const float*)d_in[4];
    const float* W2 = (const float*)d_in[5];
    const float* b2 = (const float*)d_in[6];
    float* out = (float*)d_out;

    const int N = in_sizes[0] / 128;
    const int E = in_sizes[2];
    const int* src = ei;
    const int* dst = ei + E;
    const int NB  = (N + 255) / 256;   // 196 (<=256 required by scanB)
    const int NBM = (N + 31) / 32;     // mlp tiles
    // ybf sized NBM*32 rows; tail rows unwritten (poison) but out writes guarded

    // ws layout
    float* deg      = (float*)d_ws;            // N (becomes dinv)
    int*   counts   = (int*)(deg + N);         // N
    int*   offsets  = counts + N;              // N (end-pointers post-scatter)
    int*   blockSum = offsets + N;             // 256
    int2*  sedge    = (int2*)((((uintptr_t)(blockSum + 256)) + 15) & ~(uintptr_t)15); // E
    short* W1t      = (short*)(sedge + E);     // 65536 bf16
    short* W2t      = W1t + 65536;             // 65536 bf16
    short* xbf      = (short*)((((uintptr_t)(W2t + 65536)) + 15) & ~(uintptr_t)15);   // N*128
    short* ybf      = xbf + (size_t)N * 128;   // NBM*32*128

    int nb;
    nb = (N * 32 + 255) / 256;
    k_initprep<<<nb, 256, 0, stream>>>(counts, deg, N, W1, W2, W1t, W2t, x, xbf);
    nb = (E + 255) / 256;
    k_hist<<<nb, 256, 0, stream>>>(dst, ew, counts, deg, E);
    k_scanA<<<NB, 256, 0, stream>>>(counts, offsets, blockSum, deg, N);
    k_scanB<<<1, 256, 0, stream>>>(blockSum, NB);
    k_scanC<<<NB, 256, 0, stream>>>(offsets, blockSum, N);
    nb = (E + 255) / 256;
    k_scatter<<<nb, 256, 0, stream>>>(src, dst, ew, deg, offsets, sedge, E);
    nb = (N * 64 + 255) / 256;
    k_gather<<<nb, 256, 0, stream>>>(offsets, counts, sedge, deg,
                                     (const unsigned*)xbf, (unsigned*)ybf, N);
    k_mlp<<<NBM, 256, 0, stream>>>(ybf, W1t, b1, W2t, b2, out, N);
}

// Round 14
// 270.620 us; speedup vs baseline: 8.2798x; 1.0198x over previous
//
#include <hip/hip_runtime.h>
#include <math.h>

// GCN 2-layer: out = relu( relu( (A @ x) @ W1 + b1 ) @ W2 + b2 )
// A = D^-1/2 (Adj + I) D^-1/2 (weighted, self-loop weight 1).
// Aggregation at d_in=128 ((A@x)@W1 == A@(x@W1), linearity).
// R14 = R12 resubmit (two infra failures in a row; kernel never ran).
// k_mlp 64-row tiles (halves W L2 traffic, m-repeat 2->4); gather
// unroll 8 (deeper pipeline of independent loads in latency-bound loop).

typedef __attribute__((ext_vector_type(8))) short short8v;   // 8 bf16 = 4 VGPR
typedef __attribute__((ext_vector_type(4))) float floatx4;   // MFMA C/D

__device__ __forceinline__ short f2bf(float f) {             // RNE f32->bf16
    unsigned u = __builtin_bit_cast(unsigned, f);
    unsigned r = (u + 0x7FFFu + ((u >> 16) & 1u)) >> 16;
    return (short)r;
}
__device__ __forceinline__ float bfu_lo(unsigned u) {
    return __builtin_bit_cast(float, u << 16);
}
__device__ __forceinline__ float bfu_hi(unsigned u) {
    return __builtin_bit_cast(float, u & 0xFFFF0000u);
}

// ---------------- init + weight prep + x->bf16 (merged) ----------------
__global__ __launch_bounds__(256) void k_initprep(int* __restrict__ counts,
                                                  float* __restrict__ deg, int n,
                                                  const float* __restrict__ W1,
                                                  const float* __restrict__ W2,
                                                  short* __restrict__ W1t,
                                                  short* __restrict__ W2t,
                                                  const float* __restrict__ x,
                                                  short* __restrict__ xbf) {
    int i = blockIdx.x * 256 + threadIdx.x;
    int nx4 = n * 32;
    if (i < nx4) {
        float4 v = ((const float4*)x)[i];
        short4 s;
        s.x = f2bf(v.x); s.y = f2bf(v.y); s.z = f2bf(v.z); s.w = f2bf(v.w);
        *(short4*)&xbf[(size_t)i * 4] = s;
    }
    if (i < n) { counts[i] = 0; deg[i] = 1.0f; }
    if (i < 65536) {
        int c = i >> 7, k = i & 127;
        W1t[i] = f2bf(W1[k * 512 + c]);
    } else if (i < 131072) {
        int j = i - 65536;
        int c = j >> 9, k = j & 511;
        W2t[j] = f2bf(W2[k * 128 + c]);
    }
}

__global__ __launch_bounds__(256) void k_hist(const int* __restrict__ dst,
                                              const float* __restrict__ ew,
                                              int* __restrict__ counts,
                                              float* __restrict__ deg, int E) {
    int e = blockIdx.x * 256 + threadIdx.x;
    if (e < E) {
        int d = dst[e];
        atomicAdd(&counts[d], 1);
        atomicAdd(&deg[d], ew[e]);
    }
}

__global__ __launch_bounds__(256) void k_scanA(const int* __restrict__ counts,
                                               int* __restrict__ offsets,
                                               int* __restrict__ blockSum,
                                               float* __restrict__ deg, int n) {
    __shared__ int sdata[256];
    const int tid = threadIdx.x;
    const int i = blockIdx.x * 256 + tid;
    int c = (i < n) ? counts[i] : 0;
    sdata[tid] = c;
    __syncthreads();
#pragma unroll
    for (int off = 1; off < 256; off <<= 1) {
        int t = (tid >= off) ? sdata[tid - off] : 0;
        __syncthreads();
        sdata[tid] += t;
        __syncthreads();
    }
    if (i < n) offsets[i] = sdata[tid] - c;
    if (tid == 255) blockSum[blockIdx.x] = sdata[255];
    if (i < n) {
        float d = deg[i];
        deg[i] = (d > 0.f) ? rsqrtf(d) : 0.f;
    }
}

__global__ __launch_bounds__(256) void k_scanB(int* __restrict__ blockSum, int nb) {
    __shared__ int sdata[256];
    const int tid = threadIdx.x;
    int v = (tid < nb) ? blockSum[tid] : 0;
    sdata[tid] = v;
    __syncthreads();
#pragma unroll
    for (int off = 1; off < 256; off <<= 1) {
        int t = (tid >= off) ? sdata[tid - off] : 0;
        __syncthreads();
        sdata[tid] += t;
        __syncthreads();
    }
    if (tid < nb) blockSum[tid] = sdata[tid] - v;
}

__global__ __launch_bounds__(256) void k_scanC(int* __restrict__ offsets,
                                               const int* __restrict__ blockSum, int n) {
    const int i = blockIdx.x * 256 + threadIdx.x;
    if (i < n) offsets[i] += blockSum[i >> 8];
}

// scatter edges into dst-sorted slots; bumps offsets[d] (post: end of range).
__global__ __launch_bounds__(256) void k_scatter(const int* __restrict__ src,
                                                 const int* __restrict__ dst,
                                                 const float* __restrict__ ew,
                                                 const float* __restrict__ dinv,
                                                 int* __restrict__ offsets,
                                                 int2* __restrict__ sedge, int E) {
    int e = blockIdx.x * 256 + threadIdx.x;
    if (e >= E) return;
    int s = src[e];
    int d = dst[e];
    float coef = dinv[s] * ew[e] * dinv[d];
    int pos = atomicAdd(&offsets[d], 1);
    sedge[pos] = make_int2(s, __builtin_bit_cast(int, coef));
}

// pull gather (bf16 x): one wave per node, 8x-unrolled independent loads.
__global__ __launch_bounds__(256) void k_gather(const int* __restrict__ offsets,
                                                const int* __restrict__ counts,
                                                const int2* __restrict__ sedge,
                                                const float* __restrict__ dinv,
                                                const unsigned* __restrict__ xbf_u,
                                                unsigned* __restrict__ ybf_u, int n) {
    int wid = (blockIdx.x * 256 + threadIdx.x) >> 6;
    if (wid >= n) return;
    int lane = threadIdx.x & 63;
    int o1 = offsets[wid];               // post-scatter: end of range
    int o0 = o1 - counts[wid];
    float di = dinv[wid];
    unsigned xs = xbf_u[(size_t)wid * 64 + lane];
    float2 acc;
    acc.x = di * di * bfu_lo(xs);
    acc.y = di * di * bfu_hi(xs);
    int j = o0;
    for (; j + 8 <= o1; j += 8) {
        int2 ee[8];
        unsigned vv[8];
#pragma unroll
        for (int q = 0; q < 8; ++q) ee[q] = sedge[j + q];
#pragma unroll
        for (int q = 0; q < 8; ++q) vv[q] = xbf_u[(size_t)ee[q].x * 64 + lane];
#pragma unroll
        for (int q = 0; q < 8; ++q) {
            float c = __builtin_bit_cast(float, ee[q].y);
            acc.x = fmaf(c, bfu_lo(vv[q]), acc.x);
            acc.y = fmaf(c, bfu_hi(vv[q]), acc.y);
        }
    }
    for (; j + 2 <= o1; j += 2) {
        int2 e0 = sedge[j], e1 = sedge[j + 1];
        unsigned v0 = xbf_u[(size_t)e0.x * 64 + lane];
        unsigned v1 = xbf_u[(size_t)e1.x * 64 + lane];
        float c0 = __builtin_bit_cast(float, e0.y);
        float c1 = __builtin_bit_cast(float, e1.y);
        acc.x = fmaf(c0, bfu_lo(v0), acc.x); acc.y = fmaf(c0, bfu_hi(v0), acc.y);
        acc.x = fmaf(c1, bfu_lo(v1), acc.x); acc.y = fmaf(c1, bfu_hi(v1), acc.y);
    }
    for (; j < o1; ++j) {
        int2 e = sedge[j];
        unsigned v = xbf_u[(size_t)e.x * 64 + lane];
        float c = __builtin_bit_cast(float, e.y);
        acc.x = fmaf(c, bfu_lo(v), acc.x);
        acc.y = fmaf(c, bfu_hi(v), acc.y);
    }
    unsigned lo = (unsigned)(unsigned short)f2bf(acc.x);
    unsigned hi = (unsigned)(unsigned short)f2bf(acc.y);
    ybf_u[(size_t)wid * 64 + lane] = lo | (hi << 16);
}

// ---------------- MFMA MLP: 64-row tiles ----------------
// 64 rows/block, 4 waves. y tile (16KB) staged once into swizzled LDS.
// GEMM1: wave w -> h cols [w*128,+128), m-repeat 4 (amortizes W loads).
// GEMM2: wave w -> out cols [w*32,+32). h in swizzled LDS (64KB).
// LDS 80KB -> 2 blocks/CU; launch_bounds(256,2) for VGPR headroom.
__global__ __launch_bounds__(256, 2) void k_mlp(const short* __restrict__ ybf,
                                                const short* __restrict__ W1t,
                                                const float* __restrict__ b1,
                                                const short* __restrict__ W2t,
                                                const float* __restrict__ b2,
                                                float* __restrict__ out, int n) {
    __shared__ __align__(16) short ylds[64 * 128];   // 16KB
    __shared__ __align__(16) short hlds[64 * 512];   // 64KB
    const int tid  = threadIdx.x;
    const int wave = tid >> 6;
    const int lane = tid & 63;
    const int l15  = lane & 15;
    const int lg   = lane >> 4;
    const int row0 = blockIdx.x * 64;

    // stage y tile: 1024 x 16B chunks, coalesced, XOR-swizzled store
#pragma unroll
    for (int i = 0; i < 4; ++i) {
        const int idx = tid + i * 256;       // 0..1023
        const int r   = idx >> 4;            // row 0..63
        const int c16 = idx & 15;            // 16B chunk in row
        short8v v = *(const short8v*)(ybf + (size_t)(row0 + r) * 128 + c16 * 8);
        *(short8v*)&ylds[r * 128 + ((c16 * 8) ^ ((r & 7) << 3))] = v;
    }
    __syncthreads();

    // ---- GEMM1: h[64][512] = relu(y @ W1 + b1); wave cols cb1..+127
    const int cb1 = wave * 128;
    floatx4 acc[4][8];
#pragma unroll
    for (int m = 0; m < 4; ++m)
#pragma unroll
        for (int nn = 0; nn < 8; ++nn) acc[m][nn] = (floatx4)0.0f;

#pragma unroll
    for (int kk = 0; kk < 4; ++kk) {
        const int k0 = kk * 32 + lg * 8;
        short8v bf[8];
#pragma unroll
        for (int nn = 0; nn < 8; ++nn)
            bf[nn] = *(const short8v*)(W1t + (size_t)(cb1 + nn * 16 + l15) * 128 + k0);
#pragma unroll
        for (int m = 0; m < 4; ++m) {
            const int r = m * 16 + l15;
            short8v a = *(const short8v*)&ylds[r * 128 + (k0 ^ ((r & 7) << 3))];
#pragma unroll
            for (int nn = 0; nn < 8; ++nn)
                acc[m][nn] = __builtin_amdgcn_mfma_f32_16x16x32_bf16(a, bf[nn], acc[m][nn], 0, 0, 0);
        }
    }

    // epilogue: bias + relu + bf16, swizzled LDS write
#pragma unroll
    for (int m = 0; m < 4; ++m)
#pragma unroll
        for (int nn = 0; nn < 8; ++nn) {
            const int c = cb1 + nn * 16 + l15;
            const float bb = b1[c];
#pragma unroll
            for (int i = 0; i < 4; ++i) {
                const int r = m * 16 + lg * 4 + i;
                float v = acc[m][nn][i] + bb;
                v = v > 0.f ? v : 0.f;
                hlds[r * 512 + (c ^ ((r & 7) << 3))] = f2bf(v);
            }
        }
    __syncthreads();

    // ---- GEMM2: out[64][128] = relu(h @ W2 + b2); wave cols cb2..+31
    const int cb2 = wave * 32;
    floatx4 acc2[4][2];
#pragma unroll
    for (int m = 0; m < 4; ++m)
#pragma unroll
        for (int nn = 0; nn < 2; ++nn) acc2[m][nn] = (floatx4)0.0f;

#pragma unroll
    for (int kk = 0; kk < 16; ++kk) {
        const int k0 = kk * 32 + lg * 8;
        short8v bf2[2];
#pragma unroll
        for (int nn = 0; nn < 2; ++nn)
            bf2[nn] = *(const short8v*)(W2t + (size_t)(cb2 + nn * 16 + l15) * 512 + k0);
#pragma unroll
        for (int m = 0; m < 4; ++m) {
            const int r = m * 16 + l15;
            short8v a = *(const short8v*)&hlds[r * 512 + (k0 ^ ((r & 7) << 3))];
#pragma unroll
            for (int nn = 0; nn < 2; ++nn)
                acc2[m][nn] = __builtin_amdgcn_mfma_f32_16x16x32_bf16(a, bf2[nn], acc2[m][nn], 0, 0, 0);
        }
    }

#pragma unroll
    for (int m = 0; m < 4; ++m)
#pragma unroll
        for (int nn = 0; nn < 2; ++nn) {
            const int c = cb2 + nn * 16 + l15;
            const float bb = b2[c];
#pragma unroll
            for (int i = 0; i < 4; ++i) {
                const int rg = row0 + m * 16 + lg * 4 + i;
                if (rg < n) {
                    float v = acc2[m][nn][i] + bb;
                    out[(size_t)rg * 128 + c] = v > 0.f ? v : 0.f;
                }
            }
        }
}

extern "C" void kernel_launch(void* const* d_in, const int* in_sizes, int n_in,
                              void* d_out, int out_size, void* d_ws, size_t ws_size,
                              hipStream_t stream) {
    const float* x  = (const float*)d_in[0];
    const int*   ei = (const int*)d_in[1];
    const float* ew = (const float*)d_in[2];
    const float* W1 = (const float*)d_in[3];
    const float* b1 = (const float*)d_in[4];
    const float* W2 = (const float*)d_in[5];
    const float* b2 = (const float*)d_in[6];
    float* out = (float*)d_out;

    const int N = in_sizes[0] / 128;
    const int E = in_sizes[2];
    const int* src = ei;
    const int* dst = ei + E;
    const int NB  = (N + 255) / 256;   // 196 (<=256 required by scanB)
    const int NBM = (N + 63) / 64;     // 64-row mlp tiles (782)
    // ybf sized NBM*64 rows; tail rows read as garbage but out writes guarded

    // ws layout
    float* deg      = (float*)d_ws;            // N (becomes dinv)
    int*   counts   = (int*)(deg + N);         // N
    int*   offsets  = counts + N;              // N (end-pointers post-scatter)
    int*   blockSum = offsets + N;             // 256
    int2*  sedge    = (int2*)((((uintptr_t)(blockSum + 256)) + 15) & ~(uintptr_t)15); // E
    short* W1t      = (short*)(sedge + E);     // 65536 bf16
    short* W2t      = W1t + 65536;             // 65536 bf16
    short* xbf      = (short*)((((uintptr_t)(W2t + 65536)) + 15) & ~(uintptr_t)15);   // N*128
    short* ybf      = xbf + (size_t)N * 128;   // NBM*64*128

    int nb;
    nb = (N * 32 + 255) / 256;
    k_initprep<<<nb, 256, 0, stream>>>(counts, deg, N, W1, W2, W1t, W2t, x, xbf);
    nb = (E + 255) / 256;
    k_hist<<<nb, 256, 0, stream>>>(dst, ew, counts, deg, E);
    k_scanA<<<NB, 256, 0, stream>>>(counts, offsets, blockSum, deg, N);
    k_scanB<<<1, 256, 0, stream>>>(blockSum, NB);
    k_scanC<<<NB, 256, 0, stream>>>(offsets, blockSum, N);
    nb = (E + 255) / 256;
    k_scatter<<<nb, 256, 0, stream>>>(src, dst, ew, deg, offsets, sedge, E);
    nb = (N * 64 + 255) / 256;
    k_gather<<<nb, 256, 0, stream>>>(offsets, counts, sedge, deg,
                                     (const unsigned*)xbf, (unsigned*)ybf, N);
    k_mlp<<<NBM, 256, 0, stream>>>(ybf, W1t, b1, W2t, b2, out, N);
}